// Round 5
// baseline (319.332 us; speedup 1.0000x reference)
//
#include <hip/hip_runtime.h>
#include <hip/hip_bf16.h>
#include <math.h>

typedef unsigned long long u64;
typedef unsigned short ushort_t;
typedef float f32x4 __attribute__((ext_vector_type(4)));
typedef short s16x8 __attribute__((ext_vector_type(8)));

#define NN 4096
#define NF 1024
#define NH 512
#define NC 32
#define LDP 40
#define K0 (NF + 3*NC)  // 1120
#define K1 (NH + 3*NC)  // 608

__device__ inline float bf2f(ushort_t u) {
    unsigned int v = ((unsigned int)u) << 16;
    return __uint_as_float(v);
}
__device__ inline ushort_t f2bf(float f) {
    __hip_bfloat16 h = __float2bfloat16(f);
    return *(ushort_t*)&h;
}

// ================= role: build one adj row (wave-wide) =================
__device__ void role_build(int i, int l, const float* __restrict__ adj,
                           u64* __restrict__ B1, int* __restrict__ rowcnt,
                           int* __restrict__ rowcnt_true,
                           int* __restrict__ colidx, float* __restrict__ vals) {
    const float* row = adj + (size_t)i * NN + l * 64;
    const float4* row4 = (const float4*)row;
    u64 w = 0;
    #pragma unroll
    for (int k = 0; k < 16; ++k) {
        float4 v = row4[k];
        if (v.x > 0.f) w |= 1ULL << (4*k + 0);
        if (v.y > 0.f) w |= 1ULL << (4*k + 1);
        if (v.z > 0.f) w |= 1ULL << (4*k + 2);
        if (v.w > 0.f) w |= 1ULL << (4*k + 3);
    }
    B1[(size_t)i*64 + l] = w;
    int cnt = __popcll(w);
    int pre = cnt;
    #pragma unroll
    for (int o = 1; o < 64; o <<= 1) {
        int u = __shfl_up(pre, o, 64);
        if (l >= o) pre += u;
    }
    int excl = pre - cnt;
    int total = __shfl(pre, 63, 64);
    u64 ww = w;
    int idx = excl;
    while (ww) {
        int b = __ffsll((unsigned long long)ww) - 1;
        ww &= ww - 1;
        if (idx < 64) {
            colidx[i*64 + idx] = l*64 + b;
            vals[i*64 + idx] = row[b];
        }
        ++idx;
    }
    int tot = total < 64 ? total : 64;
    for (int s = tot + l; s < 64; s += 64) {
        colidx[i*64 + s] = 0;
        vals[i*64 + s] = 0.f;
    }
    if (l == 0) {
        rowcnt_true[i] = tot;
        rowcnt[i] = (tot + 3) & ~3;
    }
}

// ================= k_setup: build | featbf | labelbits | Wt x3 | alphas =================
__global__ __launch_bounds__(256) void k_setup(const float* __restrict__ adj,
        const float* __restrict__ features, __hip_bfloat16* __restrict__ featb,
        const float* __restrict__ y, u64* __restrict__ LC,
        const float* __restrict__ W0, const float* __restrict__ W1_0,
        const float* __restrict__ W1_1,
        __hip_bfloat16* __restrict__ Wt0, __hip_bfloat16* __restrict__ Wt1,
        __hip_bfloat16* __restrict__ Wt2,
        const float* __restrict__ alphas, float* __restrict__ a_sm,
        u64* __restrict__ B1, int* __restrict__ rowcnt, int* __restrict__ rowcnt_true,
        int* __restrict__ colidx, float* __restrict__ vals) {
    __shared__ __align__(16) char smem[4352];
    int b = blockIdx.x;
    int t = threadIdx.x;
    int wid = t >> 6, l = t & 63;
    if (b < 1024) {
        role_build(b*4 + wid, l, adj, B1, rowcnt, rowcnt_true, colidx, vals);
    } else if (b < 5120) {
        int base = (b - 1024) * 1024 + t * 4;
        float4 v = *(const float4*)&features[base];
        ushort4 o;
        o.x = f2bf(v.x); o.y = f2bf(v.y); o.z = f2bf(v.z); o.w = f2bf(v.w);
        *(ushort4*)&((ushort_t*)featb)[base] = o;
    } else if (b < 5136) {
        int w = (b - 5120) * 4 + wid;
        const float* yr = y + (size_t)(w*64 + l) * NC;
        for (int c = 0; c < NC; ++c) {
            u64 m = __ballot(yr[c] > 0.5f);
            if (l == c) LC[c*64 + w] = m;
        }
    } else if (b < 6304) {
        const float* W; __hip_bfloat16* Wt; int K, ktiles, idx;
        if (b < 5696)      { W = W0;   Wt = Wt0; K = K0; ktiles = 35; idx = b - 5136; }
        else if (b < 6000) { W = W1_0; Wt = Wt1; K = K1; ktiles = 19; idx = b - 5696; }
        else               { W = W1_1; Wt = Wt2; K = K1; ktiles = 19; idx = b - 6000; }
        float (*tile)[33] = (float(*)[33])smem;
        int kb = (idx % ktiles) * 32, nb = (idx / ktiles) * 32;
        int tc = t & 31, tr8 = t >> 5;
        for (int r = tr8; r < 32; r += 8)
            tile[r][tc] = W[(size_t)(kb + r) * NH + nb + tc];
        __syncthreads();
        ushort_t* Wu = (ushort_t*)Wt;
        for (int r = tr8; r < 32; r += 8)
            Wu[(size_t)(nb + r) * K + kb + tc] = f2bf(tile[tc][r]);
    } else {
        if (t == 0) {
            for (int i = 0; i < 3; ++i) {
                float m = -1e30f;
                for (int j = 0; j < 5; ++j) m = fmaxf(m, alphas[i*5+j]);
                float e[5]; float s = 0.f;
                for (int j = 0; j < 5; ++j) { e[j] = expf(alphas[i*5+j] - m); s += e[j]; }
                for (int j = 0; j < 5; ++j) a_sm[i*5+j] = e[j] / s;
            }
        }
    }
}

// ================= role: boolean square (256 thr, one row) =================
__device__ void role_bsq(int i, int t, char* smem, const u64* __restrict__ Bidx,
                         const u64* __restrict__ Bdat, u64* __restrict__ Bout) {
    u64* ridx = (u64*)smem;            // 64
    u64* part = ridx + 64;             // 4*64
    int wid = t >> 6, lane = t & 63;
    if (t < 64) ridx[t] = Bidx[(size_t)i*64 + t];
    __syncthreads();
    u64 acc = 0;
    for (int u = wid*16; u < wid*16 + 16; ++u) {
        u64 w = ridx[u];
        while (w) {
            int k = u*64 + (__ffsll((unsigned long long)w) - 1);
            w &= (w - 1);
            acc |= Bdat[(size_t)k*64 + lane];
        }
    }
    part[wid*64 + lane] = acc;
    __syncthreads();
    if (t < 64) Bout[(size_t)i*64 + t] = part[t] | part[64+t] | part[128+t] | part[192+t];
}

// ================= role: bit transpose, one 64x64 tile per wave =================
__device__ void role_btrans(int tb, int wid, int l, char* smem,
                            const u64* __restrict__ B, u64* __restrict__ BT) {
    u64* ld = ((u64*)smem) + wid*64;
    int I = tb >> 6, J = tb & 63;
    ld[l] = B[(size_t)(I*64 + l)*64 + J];
    __syncthreads();
    u64 out = 0;
    #pragma unroll
    for (int r = 0; r < 64; ++r) out |= ((ld[r] >> l) & 1ULL) << r;
    BT[(size_t)(J*64 + l)*64 + I] = out;
}

// ================= role: ymat (8 rows/block) =================
__device__ void role_ymat(int rb, int t, char* smem, const u64* __restrict__ B,
                          const u64* __restrict__ BT, const u64* __restrict__ LC,
                          const float* __restrict__ asp, ushort_t* __restrict__ m,
                          int d, int K) {
    u64* LCt   = (u64*)smem;           // 64*32
    u64* rows  = LCt + 64*32;          // 8*64
    u64* rowsT = rows + 8*64;          // 8*64
    for (int k = t; k < 2048; k += 256) {
        int c = k >> 6, w = k & 63;
        LCt[w*32 + c] = LC[k];
    }
    for (int k = t; k < 512; k += 256) {
        int r = k >> 6, w = k & 63;
        rows[r*64 + w]  = B[(size_t)(rb + r)*64 + w];
        rowsT[r*64 + w] = BT[(size_t)(rb + r)*64 + w];
    }
    __syncthreads();
    int wid = t >> 6, lane = t & 63;
    int h = lane >> 5, c = lane & 31;
    int r = wid * 2 + h;
    int co = 0, ci = 0;
    #pragma unroll
    for (int w = 0; w < 64; ++w) {
        u64 lc = LCt[w*32 + c];
        co += __popcll(rows[r*64 + w]  & lc);
        ci += __popcll(rowsT[r*64 + w] & lc);
    }
    float a1 = asp[1], a2 = asp[2], a3 = asp[3];
    size_t i = rb + r;
    m[i*K + d + c]      = f2bf(a1 * (float)co);
    m[i*K + d + 32 + c] = f2bf(a2 * (float)ci);
    m[i*K + d + 64 + c] = f2bf(a3 * (float)(co + ci));
}

// ================= role: A2 = adj@adj numeric SpGEMM, one row per block =================
__device__ void role_a2build(int i, int t, char* smem,
                             const int* __restrict__ rowcnt_true,
                             const int* __restrict__ colidx, const float* __restrict__ vals,
                             int* __restrict__ colidx2, float* __restrict__ vals2,
                             int* __restrict__ rowcnt2) {
    float* colacc = (float*)smem;              // 4096 floats
    int* wcnt = (int*)(smem + 16384);          // 4 ints
    for (int k = t; k < 4096; k += 256) colacc[k] = 0.f;
    __syncthreads();
    int wid = t >> 6, l = t & 63;
    int cti = rowcnt_true[i];
    for (int p = 0; p < cti; ++p) {
        int j = colidx[i*64 + p];
        float vij = vals[i*64 + p];
        int ctj = rowcnt_true[j];
        if (l < ctj) {
            int k = colidx[j*64 + l];
            float vjk = vals[j*64 + l];
            if ((k >> 10) == wid) colacc[k] += vij * vjk;   // disjoint per wave & per lane
        }
    }
    __syncthreads();
    // pass 1: count nonzeros per wave region
    int cnt_w = 0;
    for (int c = 0; c < 16; ++c) {
        float v = colacc[wid*1024 + c*64 + l];
        u64 mm = __ballot(v != 0.f);
        cnt_w += __popcll(mm);
    }
    if (l == 0) wcnt[wid] = cnt_w;
    __syncthreads();
    int prefix = 0;
    for (int wq = 0; wq < wid; ++wq) prefix += wcnt[wq];
    int total = wcnt[0] + wcnt[1] + wcnt[2] + wcnt[3];
    // pass 2: compact (column-sorted, deterministic)
    int pos = prefix;
    for (int c = 0; c < 16; ++c) {
        int col = wid*1024 + c*64 + l;
        float v = colacc[col];
        u64 mm = __ballot(v != 0.f);
        if (v != 0.f) {
            int off2 = __popcll(mm & ((1ULL << l) - 1ULL));
            int s = pos + off2;
            if (s < 128) { colidx2[(size_t)i*128 + s] = col; vals2[(size_t)i*128 + s] = v; }
        }
        pos += __popcll(mm);
    }
    int tot2 = total < 128 ? total : 128;
    for (int s = tot2 + t; s < 128; s += 256) {
        colidx2[(size_t)i*128 + s] = 0;
        vals2[(size_t)i*128 + s] = 0.f;
    }
    if (t == 0) {
        int r4 = (tot2 + 3) & ~3;
        rowcnt2[i] = r4 < 128 ? r4 : 128;
    }
}

// ================= role: SpMM gather bf16 source =================
// one wave-slice: tx in [0, d/8); out[i, 0..d) += ell gather
__device__ void role_spmm_bf(int i, int tx, const int* __restrict__ rc,
                             const int* __restrict__ ci, const float* __restrict__ vl,
                             int cap, const ushort_t* __restrict__ X, int d,
                             ushort_t* __restrict__ Y, int ystride, float alpha) {
    int cnt = rc[i];
    float acc[8] = {0,0,0,0,0,0,0,0};
    for (int p = 0; p < cnt; p += 4) {
        int4   cc = *(const int4*)&ci[(size_t)i*cap + p];
        float4 vv = *(const float4*)&vl[(size_t)i*cap + p];
        s16x8 x0 = *(const s16x8*)&X[(size_t)cc.x * d + 8*tx];
        s16x8 x1 = *(const s16x8*)&X[(size_t)cc.y * d + 8*tx];
        s16x8 x2 = *(const s16x8*)&X[(size_t)cc.z * d + 8*tx];
        s16x8 x3 = *(const s16x8*)&X[(size_t)cc.w * d + 8*tx];
        #pragma unroll
        for (int j = 0; j < 8; ++j) {
            acc[j] += vv.x * bf2f((ushort_t)x0[j]);
            acc[j] += vv.y * bf2f((ushort_t)x1[j]);
            acc[j] += vv.z * bf2f((ushort_t)x2[j]);
            acc[j] += vv.w * bf2f((ushort_t)x3[j]);
        }
    }
    s16x8 o;
    #pragma unroll
    for (int j = 0; j < 8; ++j) o[j] = (short)f2bf(alpha * acc[j]);
    *(s16x8*)&Y[(size_t)i*ystride + 8*tx] = o;
}

// ================= role: SpMM gather fp32 source with on-the-fly l2 scale =================
// src is [NN][NH] fp32 (unnormalized GEMM out); parts is [NN][8] partial sumsq
__device__ void role_spmm_f32s(int i, int tx, const int* __restrict__ rc,
                               const int* __restrict__ ci, const float* __restrict__ vl,
                               const float* __restrict__ src, const float* __restrict__ parts,
                               int ln, ushort_t* __restrict__ Y, int ystride, float alpha) {
    int cnt = rc[i];
    float acc[8] = {0,0,0,0,0,0,0,0};
    for (int p = 0; p < cnt; p += 4) {
        int4   cc = *(const int4*)&ci[(size_t)i*128 + p];
        float4 vv = *(const float4*)&vl[(size_t)i*128 + p];
        int cols[4] = {cc.x, cc.y, cc.z, cc.w};
        float vs4[4] = {vv.x, vv.y, vv.z, vv.w};
        #pragma unroll
        for (int e = 0; e < 4; ++e) {
            int col = cols[e];
            float4 pa = *(const float4*)&parts[col*8];
            float4 pb = *(const float4*)&parts[col*8 + 4];
            float ss = pa.x+pa.y+pa.z+pa.w + pb.x+pb.y+pb.z+pb.w;
            float sc = ln ? 1.0f / fmaxf(sqrtf(ss), 1e-12f) : 1.0f;
            float vsc = vs4[e] * sc;
            float4 xa = *(const float4*)&src[(size_t)col*NH + 8*tx];
            float4 xb = *(const float4*)&src[(size_t)col*NH + 8*tx + 4];
            acc[0] += vsc*xa.x; acc[1] += vsc*xa.y; acc[2] += vsc*xa.z; acc[3] += vsc*xa.w;
            acc[4] += vsc*xb.x; acc[5] += vsc*xb.y; acc[6] += vsc*xb.z; acc[7] += vsc*xb.w;
        }
    }
    s16x8 o;
    #pragma unroll
    for (int j = 0; j < 8; ++j) o[j] = (short)f2bf(alpha * acc[j]);
    *(s16x8*)&Y[(size_t)i*ystride + 8*tx] = o;
}

// ================= role: MFMA GEMM 64x64 tile + parts epilogue =================
__device__ void role_gemm(int bx, int tid, char* smem,
                          const ushort_t* __restrict__ mat, const ushort_t* __restrict__ Wt,
                          const float* __restrict__ bias, float* __restrict__ C,
                          float* __restrict__ parts, int K) {
    ushort_t* As = (ushort_t*)smem;
    ushort_t* Bs = As + 64*LDP;
    int xcd = bx & 7, rest = bx >> 3;
    int nt = rest & 7, mt = (rest >> 3) * 8 + xcd;
    int bm = mt * 64, bn = nt * 64;
    int srow = tid >> 2, scol = (tid & 3) * 8;
    int wid = tid >> 6, lane = tid & 63;
    int fr = lane & 15, hi2 = lane >> 4, fk = hi2 * 8;
    f32x4 acc[4] = {{0,0,0,0},{0,0,0,0},{0,0,0,0},{0,0,0,0}};
    const ushort_t* Au = mat + (size_t)(bm + srow) * K + scol;
    const ushort_t* Bu = Wt  + (size_t)(bn + srow) * K + scol;
    for (int k0 = 0; k0 < K; k0 += 32) {
        *(s16x8*)&As[srow * LDP + scol] = *(const s16x8*)(Au + k0);
        *(s16x8*)&Bs[srow * LDP + scol] = *(const s16x8*)(Bu + k0);
        __syncthreads();
        s16x8 af = *(const s16x8*)&As[(wid * 16 + fr) * LDP + fk];
        #pragma unroll
        for (int j = 0; j < 4; ++j) {
            s16x8 bfv = *(const s16x8*)&Bs[(j * 16 + fr) * LDP + fk];
            acc[j] = __builtin_amdgcn_mfma_f32_16x16x32_bf16(af, bfv, acc[j], 0, 0, 0);
        }
        __syncthreads();
    }
    int drow = bm + wid * 16 + hi2 * 4;
    // per-row partial sum of squares over this block's 64 cols
    #pragma unroll
    for (int r = 0; r < 4; ++r) {
        float ps = 0.f;
        #pragma unroll
        for (int j = 0; j < 4; ++j) ps += acc[j][r] * acc[j][r];
        // add bias first? No: sumsq must be of (acc + bias). Include bias below.
        ps = 0.f;
        #pragma unroll
        for (int j = 0; j < 4; ++j) {
            float v = acc[j][r] + bias[bn + j*16 + fr];
            ps += v * v;
        }
        #pragma unroll
        for (int o = 1; o < 16; o <<= 1) ps += __shfl_xor(ps, o, 64);
        if (fr == 0) parts[(size_t)(drow + r) * 8 + nt] = ps;
    }
    #pragma unroll
    for (int j = 0; j < 4; ++j) {
        int col = bn + j * 16 + fr;
        float bv = bias[col];
        #pragma unroll
        for (int r = 0; r < 4; ++r)
            C[(size_t)(drow + r) * NH + col] = acc[j][r] + bv;
    }
}

// ================= phase kernels =================
__global__ __launch_bounds__(256) void k_phase2(const u64* __restrict__ B1, u64* __restrict__ B2,
        u64* __restrict__ B1T,
        const int* __restrict__ rowcnt_true, const int* __restrict__ colidx,
        const float* __restrict__ vals,
        int* __restrict__ colidx2, float* __restrict__ vals2, int* __restrict__ rowcnt2,
        const int* __restrict__ rowcnt, const __hip_bfloat16* __restrict__ featb,
        __hip_bfloat16* __restrict__ mat0, const float* __restrict__ a_sm) {
    __shared__ __align__(16) char smem[16512];
    int b = blockIdx.x;
    int t = threadIdx.x;
    int wid = t >> 6, l = t & 63;
    if (b < 4096) {
        role_bsq(b, t, smem, B1, B1, B2);
    } else if (b < 5120) {
        role_btrans((b - 4096)*4 + wid, wid, l, smem, B1, B1T);
    } else if (b < 9216) {
        role_a2build(b - 5120, t, smem, rowcnt_true, colidx, vals, colidx2, vals2, rowcnt2);
    } else {
        int idx = b - 9216;                 // 2048 blocks, 2 rows each
        int ty = t >> 7, tx = t & 127;
        role_spmm_bf(idx*2 + ty, tx, rowcnt, colidx, vals, 64,
                     (const ushort_t*)featb, NF, (ushort_t*)mat0, K0, a_sm[0]);
    }
}

__global__ __launch_bounds__(256) void k_phase3(const u64* __restrict__ B2, u64* __restrict__ B4,
        u64* __restrict__ B2T, const u64* __restrict__ B1, const u64* __restrict__ B1T,
        const u64* __restrict__ LC, const float* __restrict__ a_sm,
        __hip_bfloat16* __restrict__ mat0) {
    __shared__ __align__(16) char smem[24576];
    int b = blockIdx.x;
    int t = threadIdx.x;
    int wid = t >> 6, l = t & 63;
    if (b < 4096) {
        role_bsq(b, t, smem, B2, B2, B4);
    } else if (b < 5120) {
        role_btrans((b - 4096)*4 + wid, wid, l, smem, B2, B2T);
    } else {
        role_ymat((b - 5120)*8, t, smem, B1, B1T, LC, a_sm, (ushort_t*)mat0, NF, K0);
    }
}

__global__ __launch_bounds__(256) void k_phase4(const __hip_bfloat16* __restrict__ mat0,
        const __hip_bfloat16* __restrict__ Wt0, const float* __restrict__ b0,
        float* __restrict__ tmp0, float* __restrict__ parts0,
        const u64* __restrict__ B4, u64* __restrict__ B4T,
        const u64* __restrict__ B2, const u64* __restrict__ B2T,
        const u64* __restrict__ LC, const float* __restrict__ a_sm,
        __hip_bfloat16* __restrict__ mat1) {
    __shared__ __align__(16) char smem[24576];
    int b = blockIdx.x;
    int t = threadIdx.x;
    int wid = t >> 6, l = t & 63;
    if (b < 512) {
        role_gemm(b, t, smem, (const ushort_t*)mat0, (const ushort_t*)Wt0, b0,
                  tmp0, parts0, K0);
    } else if (b < 1536) {
        role_btrans((b - 512)*4 + wid, wid, l, smem, B4, B4T);
    } else {
        role_ymat((b - 1536)*8, t, smem, B2, B2T, LC, a_sm + 5, (ushort_t*)mat1, NH, K1);
    }
}

__global__ __launch_bounds__(256) void k_phase5(const int* __restrict__ rowcnt2,
        const int* __restrict__ colidx2, const float* __restrict__ vals2,
        const float* __restrict__ tmp0, const float* __restrict__ parts0,
        const int* __restrict__ lnflag, __hip_bfloat16* __restrict__ mat1,
        const u64* __restrict__ B4, const u64* __restrict__ B4T,
        const u64* __restrict__ LC, const float* __restrict__ a_sm,
        __hip_bfloat16* __restrict__ mat2) {
    __shared__ __align__(16) char smem[24576];
    int b = blockIdx.x;
    int t = threadIdx.x;
    if (b < 1024) {
        int i = b*4 + (t >> 6), tx = t & 63;
        role_spmm_f32s(i, tx, rowcnt2, colidx2, vals2, tmp0, parts0, *lnflag,
                       (ushort_t*)mat1, K1, a_sm[5]);
    } else {
        role_ymat((b - 1024)*8, t, smem, B4, B4T, LC, a_sm + 10, (ushort_t*)mat2, NH, K1);
    }
}

__global__ __launch_bounds__(256) void k_gemm(const __hip_bfloat16* __restrict__ mat,
        const __hip_bfloat16* __restrict__ Wt, const float* __restrict__ bias,
        float* __restrict__ C, float* __restrict__ parts, int K) {
    __shared__ __align__(16) char smem[2 * 64 * LDP * 2];
    role_gemm(blockIdx.x, threadIdx.x, smem, (const ushort_t*)mat, (const ushort_t*)Wt,
              bias, C, parts, K);
}

__global__ __launch_bounds__(256) void k_spmm_f(const int* __restrict__ rc2,
        const int* __restrict__ ci2, const float* __restrict__ vl2,
        const float* __restrict__ src, const float* __restrict__ parts,
        const int* __restrict__ lnflag, __hip_bfloat16* __restrict__ Y,
        int ystride, const float* __restrict__ a_sm, int ai) {
    int i = blockIdx.x*4 + (threadIdx.x >> 6), tx = threadIdx.x & 63;
    float alpha = (ai >= 0) ? a_sm[ai] : 1.0f;
    role_spmm_f32s(i, tx, rc2, ci2, vl2, src, parts, *lnflag, (ushort_t*)Y, ystride, alpha);
}

__global__ __launch_bounds__(256) void k_spmm_b(const int* __restrict__ rc2,
        const int* __restrict__ ci2, const float* __restrict__ vl2,
        const __hip_bfloat16* __restrict__ X, __hip_bfloat16* __restrict__ Y,
        int ystride, const float* __restrict__ a_sm, int ai) {
    int i = blockIdx.x*4 + (threadIdx.x >> 6), tx = threadIdx.x & 63;
    float alpha = (ai >= 0) ? a_sm[ai] : 1.0f;
    role_spmm_bf(i, tx, rc2, ci2, vl2, 128, (const ushort_t*)X, NH, (ushort_t*)Y,
                 ystride, alpha);
}

// ================= final: all-layer l2norm + max + relu + W2 + log_softmax =================
__global__ __launch_bounds__(256) void k_l2final(const float* __restrict__ tmp0,
        const float* __restrict__ parts0, const float* __restrict__ tmp1,
        const float* __restrict__ parts1, const float* __restrict__ tmp2,
        const float* __restrict__ parts2, const float* __restrict__ feat0,
        const float* __restrict__ W2, const float* __restrict__ b2,
        const int* __restrict__ lnflag, float* __restrict__ out) {
    int rb = blockIdx.x * 8;
    int t = threadIdx.x;
    __shared__ float rows[8][NF + NH];
    __shared__ float part[8][8][32];
    for (int r = 0; r < 8; ++r) {
        const float* f0 = feat0 + (size_t)(rb + r) * NF;
        for (int c = t; c < NF; c += 256) rows[r][c] = fmaxf(f0[c], 0.f);
    }
    int wid = t >> 6, lane = t & 63;
    int ln = *lnflag;
    #pragma unroll
    for (int rr = 0; rr < 2; ++rr) {
        int r = wid * 2 + rr;
        int row = rb + r;
        float s0, s1, s2;
        {
            float4 a0 = *(const float4*)&parts0[row*8], b0v = *(const float4*)&parts0[row*8+4];
            float4 a1 = *(const float4*)&parts1[row*8], b1v = *(const float4*)&parts1[row*8+4];
            float4 a2 = *(const float4*)&parts2[row*8], b2v = *(const float4*)&parts2[row*8+4];
            float q0 = a0.x+a0.y+a0.z+a0.w + b0v.x+b0v.y+b0v.z+b0v.w;
            float q1 = a1.x+a1.y+a1.z+a1.w + b1v.x+b1v.y+b1v.z+b1v.w;
            float q2 = a2.x+a2.y+a2.z+a2.w + b2v.x+b2v.y+b2v.z+b2v.w;
            s0 = ln ? 1.0f / fmaxf(sqrtf(q0), 1e-12f) : 1.0f;
            s1 = ln ? 1.0f / fmaxf(sqrtf(q1), 1e-12f) : 1.0f;
            s2 = ln ? 1.0f / fmaxf(sqrtf(q2), 1e-12f) : 1.0f;
        }
        const float4* t0 = (const float4*)(tmp0 + (size_t)row * NH + lane * 8);
        const float4* t1 = (const float4*)(tmp1 + (size_t)row * NH + lane * 8);
        const float4* t2 = (const float4*)(tmp2 + (size_t)row * NH + lane * 8);
        float* dst = &rows[r][NF + lane * 8];
        #pragma unroll
        for (int h = 0; h < 2; ++h) {
            float4 v0 = t0[h], v1 = t1[h], v2 = t2[h];
            dst[h*4+0] = fmaxf(fmaxf(fmaxf(v0.x*s0, v1.x*s1), v2.x*s2), 0.f);
            dst[h*4+1] = fmaxf(fmaxf(fmaxf(v0.y*s0, v1.y*s1), v2.y*s2), 0.f);
            dst[h*4+2] = fmaxf(fmaxf(fmaxf(v0.z*s0, v1.z*s1), v2.z*s2), 0.f);
            dst[h*4+3] = fmaxf(fmaxf(fmaxf(v0.w*s0, v1.w*s1), v2.w*s2), 0.f);
        }
    }
    __syncthreads();
    int c = t & 31, g = t >> 5;
    float acc[8] = {0,0,0,0,0,0,0,0};
    for (int k = g * 192; k < (g + 1) * 192; ++k) {
        float w = W2[(size_t)k * NC + c];
        #pragma unroll
        for (int r = 0; r < 8; ++r) acc[r] += rows[r][k] * w;
    }
    #pragma unroll
    for (int r = 0; r < 8; ++r) part[g][r][c] = acc[r];
    __syncthreads();
    int r = g;
    float lg = b2[c];
    #pragma unroll
    for (int gg = 0; gg < 8; ++gg) lg += part[gg][r][c];
    float m = lg;
    #pragma unroll
    for (int o = 16; o > 0; o >>= 1) m = fmaxf(m, __shfl_xor(m, o, 32));
    float e = expf(lg - m), s = e;
    #pragma unroll
    for (int o = 16; o > 0; o >>= 1) s += __shfl_xor(s, o, 32);
    out[(size_t)(rb + r) * NC + c] = lg - m - logf(s);
}

extern "C" void kernel_launch(void* const* d_in, const int* in_sizes, int n_in,
                              void* d_out, int out_size, void* d_ws, size_t ws_size,
                              hipStream_t stream) {
    const float* adj      = (const float*)d_in[0];
    const float* features = (const float*)d_in[1];
    const float* y        = (const float*)d_in[2];
    const float* W0       = (const float*)d_in[3];
    const float* b0       = (const float*)d_in[4];
    const float* W1_0     = (const float*)d_in[5];
    const float* b1_0     = (const float*)d_in[6];
    const float* W1_1     = (const float*)d_in[7];
    const float* b1_1     = (const float*)d_in[8];
    const float* W2       = (const float*)d_in[9];
    const float* b2       = (const float*)d_in[10];
    const float* alphas   = (const float*)d_in[11];
    const int*   lnflag   = (const int*)d_in[12];
    float* out = (float*)d_out;

    char* ws = (char*)d_ws;
    size_t off = 0;
    auto alloc = [&](size_t bytes) -> char* {
        char* p = ws + off;
        off = (off + bytes + 255) & ~(size_t)255;
        return p;
    };
    float* a_sm        = (float*)alloc(16 * 4);
    int*   rowcnt      = (int*)alloc((size_t)NN * 4);
    int*   rowcnt_true = (int*)alloc((size_t)NN * 4);
    int*   colidx      = (int*)alloc((size_t)NN * 64 * 4);
    float* vals        = (float*)alloc((size_t)NN * 64 * 4);
    int*   colidx2     = (int*)alloc((size_t)NN * 128 * 4);
    float* vals2       = (float*)alloc((size_t)NN * 128 * 4);
    int*   rowcnt2     = (int*)alloc((size_t)NN * 4);
    u64* B1  = (u64*)alloc((size_t)NN * 64 * 8);
    u64* B2  = (u64*)alloc((size_t)NN * 64 * 8);
    u64* B4  = (u64*)alloc((size_t)NN * 64 * 8);
    u64* B1T = (u64*)alloc((size_t)NN * 64 * 8);
    u64* B2T = (u64*)alloc((size_t)NN * 64 * 8);
    u64* B4T = (u64*)alloc((size_t)NN * 64 * 8);
    u64* LC  = (u64*)alloc((size_t)NC * 64 * 8);
    __hip_bfloat16* featb = (__hip_bfloat16*)alloc((size_t)NN * NF * 2);
    __hip_bfloat16* t1b   = (__hip_bfloat16*)alloc((size_t)NN * NH * 2);
    __hip_bfloat16* mat0  = (__hip_bfloat16*)alloc((size_t)NN * K0 * 2);
    __hip_bfloat16* mat1  = (__hip_bfloat16*)alloc((size_t)NN * K1 * 2);
    __hip_bfloat16* mat2  = (__hip_bfloat16*)alloc((size_t)NN * K1 * 2);
    __hip_bfloat16* Wt0   = (__hip_bfloat16*)alloc((size_t)NH * K0 * 2);
    __hip_bfloat16* Wt1   = (__hip_bfloat16*)alloc((size_t)NH * K1 * 2);
    __hip_bfloat16* Wt2   = (__hip_bfloat16*)alloc((size_t)NH * K1 * 2);
    float* tmp0   = (float*)alloc((size_t)NN * NH * 4);
    float* tmp1   = (float*)alloc((size_t)NN * NH * 4);
    float* tmp2   = (float*)alloc((size_t)NN * NH * 4);
    float* parts0 = (float*)alloc((size_t)NN * 8 * 4);
    float* parts1 = (float*)alloc((size_t)NN * 8 * 4);
    float* parts2 = (float*)alloc((size_t)NN * 8 * 4);

    // L1: build + prep
    k_setup<<<6305, 256, 0, stream>>>(adj, features, featb, y, LC, W0, W1_0, W1_1,
                                      Wt0, Wt1, Wt2, alphas, a_sm,
                                      B1, rowcnt, rowcnt_true, colidx, vals);
    // L2: bsq(B1->B2) | btrans(B1) | A2 spgemm | spmm0
    k_phase2<<<11264, 256, 0, stream>>>(B1, B2, B1T, rowcnt_true, colidx, vals,
                                        colidx2, vals2, rowcnt2, rowcnt, featb, mat0, a_sm);
    // L3: bsq(B2->B4) | btrans(B2) | ymat L0
    k_phase3<<<5632, 256, 0, stream>>>(B2, B4, B2T, B1, B1T, LC, a_sm, mat0);
    // L4: gemm0 | btrans(B4) | ymat L1
    k_phase4<<<2048, 256, 0, stream>>>(mat0, Wt0, b0, tmp0, parts0,
                                       B4, B4T, B2, B2T, LC, a_sm, mat1);
    // L5: spmm1 (A2 on tmp0/scale) | ymat L2
    k_phase5<<<1536, 256, 0, stream>>>(rowcnt2, colidx2, vals2, tmp0, parts0, lnflag,
                                       mat1, B4, B4T, LC, a_sm, mat2);
    // L6: gemm1
    k_gemm<<<512, 256, 0, stream>>>(mat1, Wt1, b1_0, tmp1, parts1, K1);
    // L7: spmm2a (A2 on tmp1/scale -> t1b)
    k_spmm_f<<<NN/4, 256, 0, stream>>>(rowcnt2, colidx2, vals2, tmp1, parts1, lnflag,
                                       t1b, NH, a_sm, -1);
    // L8: spmm2b (A2 on t1b -> mat2 hop cols, x alpha20)
    k_spmm_b<<<NN/4, 256, 0, stream>>>(rowcnt2, colidx2, vals2, t1b, mat2, K1, a_sm, 10);
    // L9: gemm2
    k_gemm<<<512, 256, 0, stream>>>(mat2, Wt2, b1_1, tmp2, parts2, K1);
    // L10: fused final
    k_l2final<<<NN/8, 256, 0, stream>>>(tmp0, parts0, tmp1, parts1, tmp2, parts2,
                                        features, W2, b2, lnflag, out);
}

// Round 6
// 215.483 us; speedup vs baseline: 1.4819x; 1.4819x over previous
//
#include <hip/hip_runtime.h>
#include <hip/hip_bf16.h>
#include <math.h>

typedef unsigned long long u64;
typedef unsigned short ushort_t;
typedef float f32x4 __attribute__((ext_vector_type(4)));
typedef short s16x8 __attribute__((ext_vector_type(8)));

#define NN 4096
#define NF 1024
#define NH 512
#define NC 32
#define LDP 40
#define K0 (NF + 3*NC)  // 1120
#define K1 (NH + 3*NC)  // 608

__device__ inline float bf2f(ushort_t u) {
    unsigned int v = ((unsigned int)u) << 16;
    return __uint_as_float(v);
}
__device__ inline ushort_t f2bf(float f) {
    __hip_bfloat16 h = __float2bfloat16(f);
    return *(ushort_t*)&h;
}

// ================= role: build one adj row (wave-wide) =================
__device__ void role_build(int i, int l, const float* __restrict__ adj,
                           u64* __restrict__ B1, int* __restrict__ rowcnt,
                           int* __restrict__ colidx, float* __restrict__ vals) {
    const float* row = adj + (size_t)i * NN + l * 64;
    const float4* row4 = (const float4*)row;
    u64 w = 0;
    #pragma unroll
    for (int k = 0; k < 16; ++k) {
        float4 v = row4[k];
        if (v.x > 0.f) w |= 1ULL << (4*k + 0);
        if (v.y > 0.f) w |= 1ULL << (4*k + 1);
        if (v.z > 0.f) w |= 1ULL << (4*k + 2);
        if (v.w > 0.f) w |= 1ULL << (4*k + 3);
    }
    B1[(size_t)i*64 + l] = w;
    int cnt = __popcll(w);
    int pre = cnt;
    #pragma unroll
    for (int o = 1; o < 64; o <<= 1) {
        int u = __shfl_up(pre, o, 64);
        if (l >= o) pre += u;
    }
    int excl = pre - cnt;
    int total = __shfl(pre, 63, 64);
    u64 ww = w;
    int idx = excl;
    while (ww) {
        int b = __ffsll((unsigned long long)ww) - 1;
        ww &= ww - 1;
        if (idx < 64) {
            colidx[i*64 + idx] = l*64 + b;
            vals[i*64 + idx] = row[b];
        }
        ++idx;
    }
    int tot = total < 64 ? total : 64;
    for (int s = tot + l; s < 64; s += 64) {
        colidx[i*64 + s] = 0;
        vals[i*64 + s] = 0.f;
    }
    if (l == 0) rowcnt[i] = (tot + 3) & ~3;
}

// ================= k_setup: build | featbf | labelbits | Wt x3 | alphas =================
__global__ __launch_bounds__(256) void k_setup(const float* __restrict__ adj,
        const float* __restrict__ features, __hip_bfloat16* __restrict__ featb,
        const float* __restrict__ y, u64* __restrict__ LC,
        const float* __restrict__ W0, const float* __restrict__ W1_0,
        const float* __restrict__ W1_1,
        __hip_bfloat16* __restrict__ Wt0, __hip_bfloat16* __restrict__ Wt1,
        __hip_bfloat16* __restrict__ Wt2,
        const float* __restrict__ alphas, float* __restrict__ a_sm,
        u64* __restrict__ B1, int* __restrict__ rowcnt,
        int* __restrict__ colidx, float* __restrict__ vals) {
    __shared__ __align__(16) char smem[4352];
    int b = blockIdx.x;
    int t = threadIdx.x;
    int wid = t >> 6, l = t & 63;
    if (b < 1024) {
        role_build(b*4 + wid, l, adj, B1, rowcnt, colidx, vals);
    } else if (b < 5120) {
        int base = (b - 1024) * 1024 + t * 4;
        float4 v = *(const float4*)&features[base];
        ushort4 o;
        o.x = f2bf(v.x); o.y = f2bf(v.y); o.z = f2bf(v.z); o.w = f2bf(v.w);
        *(ushort4*)&((ushort_t*)featb)[base] = o;
    } else if (b < 5136) {
        int w = (b - 5120) * 4 + wid;
        const float* yr = y + (size_t)(w*64 + l) * NC;
        for (int c = 0; c < NC; ++c) {
            u64 m = __ballot(yr[c] > 0.5f);
            if (l == c) LC[c*64 + w] = m;
        }
    } else if (b < 6304) {
        const float* W; __hip_bfloat16* Wt; int K, ktiles, idx;
        if (b < 5696)      { W = W0;   Wt = Wt0; K = K0; ktiles = 35; idx = b - 5136; }
        else if (b < 6000) { W = W1_0; Wt = Wt1; K = K1; ktiles = 19; idx = b - 5696; }
        else               { W = W1_1; Wt = Wt2; K = K1; ktiles = 19; idx = b - 6000; }
        float (*tile)[33] = (float(*)[33])smem;
        int kb = (idx % ktiles) * 32, nb = (idx / ktiles) * 32;
        int tc = t & 31, tr8 = t >> 5;
        for (int r = tr8; r < 32; r += 8)
            tile[r][tc] = W[(size_t)(kb + r) * NH + nb + tc];
        __syncthreads();
        ushort_t* Wu = (ushort_t*)Wt;
        for (int r = tr8; r < 32; r += 8)
            Wu[(size_t)(nb + r) * K + kb + tc] = f2bf(tile[tc][r]);
    } else {
        if (t == 0) {
            for (int i = 0; i < 3; ++i) {
                float m = -1e30f;
                for (int j = 0; j < 5; ++j) m = fmaxf(m, alphas[i*5+j]);
                float e[5]; float s = 0.f;
                for (int j = 0; j < 5; ++j) { e[j] = expf(alphas[i*5+j] - m); s += e[j]; }
                for (int j = 0; j < 5; ++j) a_sm[i*5+j] = e[j] / s;
            }
        }
    }
}

// ================= role: boolean product row: Bout[i] = OR_{k in bits(Bidx[i])} Bdat[k] ====
__device__ void role_bsq(int i, int t, char* smem, const u64* __restrict__ Bidx,
                         const u64* __restrict__ Bdat, u64* __restrict__ Bout) {
    u64* ridx = (u64*)smem;            // 64
    u64* part = ridx + 64;             // 4*64
    int wid = t >> 6, lane = t & 63;
    if (t < 64) ridx[t] = Bidx[(size_t)i*64 + t];
    __syncthreads();
    u64 acc = 0;
    for (int u = wid*16; u < wid*16 + 16; ++u) {
        u64 w = ridx[u];
        while (w) {
            int k = u*64 + (__ffsll((unsigned long long)w) - 1);
            w &= (w - 1);
            acc |= Bdat[(size_t)k*64 + lane];
        }
    }
    part[wid*64 + lane] = acc;
    __syncthreads();
    if (t < 64) Bout[(size_t)i*64 + t] = part[t] | part[64+t] | part[128+t] | part[192+t];
}

// ================= role: bit transpose, one 64x64 tile per wave =================
__device__ void role_btrans(int tb, int wid, int l, char* smem,
                            const u64* __restrict__ B, u64* __restrict__ BT) {
    u64* ld = ((u64*)smem) + wid*64;
    int I = tb >> 6, J = tb & 63;
    ld[l] = B[(size_t)(I*64 + l)*64 + J];
    __syncthreads();
    u64 out = 0;
    #pragma unroll
    for (int r = 0; r < 64; ++r) out |= ((ld[r] >> l) & 1ULL) << r;
    BT[(size_t)(J*64 + l)*64 + I] = out;
}

// ================= role: ymat (8 rows/block) =================
__device__ void role_ymat(int rb, int t, char* smem, const u64* __restrict__ B,
                          const u64* __restrict__ BT, const u64* __restrict__ LC,
                          const float* __restrict__ asp, ushort_t* __restrict__ m,
                          int d, int K) {
    u64* LCt   = (u64*)smem;           // 64*32
    u64* rows  = LCt + 64*32;          // 8*64
    u64* rowsT = rows + 8*64;          // 8*64
    for (int k = t; k < 2048; k += 256) {
        int c = k >> 6, w = k & 63;
        LCt[w*32 + c] = LC[k];
    }
    for (int k = t; k < 512; k += 256) {
        int r = k >> 6, w = k & 63;
        rows[r*64 + w]  = B[(size_t)(rb + r)*64 + w];
        rowsT[r*64 + w] = BT[(size_t)(rb + r)*64 + w];
    }
    __syncthreads();
    int wid = t >> 6, lane = t & 63;
    int h = lane >> 5, c = lane & 31;
    int r = wid * 2 + h;
    int co = 0, ci = 0;
    #pragma unroll
    for (int w = 0; w < 64; ++w) {
        u64 lc = LCt[w*32 + c];
        co += __popcll(rows[r*64 + w]  & lc);
        ci += __popcll(rowsT[r*64 + w] & lc);
    }
    float a1 = asp[1], a2 = asp[2], a3 = asp[3];
    size_t i = rb + r;
    m[i*K + d + c]      = f2bf(a1 * (float)co);
    m[i*K + d + 32 + c] = f2bf(a2 * (float)ci);
    m[i*K + d + 64 + c] = f2bf(a3 * (float)(co + ci));
}

// ================= role: SpMM gather, bf16 source (ELL cap 64) =================
__device__ void role_spmm_bf(int i, int tx, const int* __restrict__ rc,
                             const int* __restrict__ ci, const float* __restrict__ vl,
                             const ushort_t* __restrict__ X, int d,
                             ushort_t* __restrict__ Y, int ystride, float alpha) {
    int cnt = rc[i];
    float acc[8] = {0,0,0,0,0,0,0,0};
    for (int p = 0; p < cnt; p += 4) {
        int4   cc = *(const int4*)&ci[(size_t)i*64 + p];
        float4 vv = *(const float4*)&vl[(size_t)i*64 + p];
        s16x8 x0 = *(const s16x8*)&X[(size_t)cc.x * d + 8*tx];
        s16x8 x1 = *(const s16x8*)&X[(size_t)cc.y * d + 8*tx];
        s16x8 x2 = *(const s16x8*)&X[(size_t)cc.z * d + 8*tx];
        s16x8 x3 = *(const s16x8*)&X[(size_t)cc.w * d + 8*tx];
        #pragma unroll
        for (int j = 0; j < 8; ++j) {
            acc[j] += vv.x * bf2f((ushort_t)x0[j]);
            acc[j] += vv.y * bf2f((ushort_t)x1[j]);
            acc[j] += vv.z * bf2f((ushort_t)x2[j]);
            acc[j] += vv.w * bf2f((ushort_t)x3[j]);
        }
    }
    s16x8 o;
    #pragma unroll
    for (int j = 0; j < 8; ++j) o[j] = (short)f2bf(alpha * acc[j]);
    *(s16x8*)&Y[(size_t)i*ystride + 8*tx] = o;
}

// ================= role: SpMM gather, fp32 source with inline l2 normalize =================
__device__ void role_spmm_f32s(int i, int tx, const int* __restrict__ rc,
                               const int* __restrict__ ci, const float* __restrict__ vl,
                               const float* __restrict__ src, const float* __restrict__ parts,
                               int ln, ushort_t* __restrict__ Y, int ystride, float alpha) {
    int cnt = rc[i];
    float acc[8] = {0,0,0,0,0,0,0,0};
    for (int p = 0; p < cnt; p += 4) {
        int4   cc = *(const int4*)&ci[(size_t)i*64 + p];
        float4 vv = *(const float4*)&vl[(size_t)i*64 + p];
        int cols[4] = {cc.x, cc.y, cc.z, cc.w};
        float vs4[4] = {vv.x, vv.y, vv.z, vv.w};
        #pragma unroll
        for (int e = 0; e < 4; ++e) {
            int col = cols[e];
            float4 pa = *(const float4*)&parts[col*8];
            float4 pb = *(const float4*)&parts[col*8 + 4];
            float ss = pa.x+pa.y+pa.z+pa.w + pb.x+pb.y+pb.z+pb.w;
            float sc = ln ? 1.0f / fmaxf(sqrtf(ss), 1e-12f) : 1.0f;
            float vsc = vs4[e] * sc;
            float4 xa = *(const float4*)&src[(size_t)col*NH + 8*tx];
            float4 xb = *(const float4*)&src[(size_t)col*NH + 8*tx + 4];
            acc[0] += vsc*xa.x; acc[1] += vsc*xa.y; acc[2] += vsc*xa.z; acc[3] += vsc*xa.w;
            acc[4] += vsc*xb.x; acc[5] += vsc*xb.y; acc[6] += vsc*xb.z; acc[7] += vsc*xb.w;
        }
    }
    s16x8 o;
    #pragma unroll
    for (int j = 0; j < 8; ++j) o[j] = (short)f2bf(alpha * acc[j]);
    *(s16x8*)&Y[(size_t)i*ystride + 8*tx] = o;
}

// ================= role: MFMA GEMM 64x64 tile + parts epilogue =================
__device__ void role_gemm(int bx, int tid, char* smem,
                          const ushort_t* __restrict__ mat, const ushort_t* __restrict__ Wt,
                          const float* __restrict__ bias, float* __restrict__ C,
                          float* __restrict__ parts, int K) {
    ushort_t* As = (ushort_t*)smem;
    ushort_t* Bs = As + 64*LDP;
    int xcd = bx & 7, rest = bx >> 3;
    int nt = rest & 7, mt = (rest >> 3) * 8 + xcd;
    int bm = mt * 64, bn = nt * 64;
    int srow = tid >> 2, scol = (tid & 3) * 8;
    int wid = tid >> 6, lane = tid & 63;
    int fr = lane & 15, hi2 = lane >> 4, fk = hi2 * 8;
    f32x4 acc[4] = {{0,0,0,0},{0,0,0,0},{0,0,0,0},{0,0,0,0}};
    const ushort_t* Au = mat + (size_t)(bm + srow) * K + scol;
    const ushort_t* Bu = Wt  + (size_t)(bn + srow) * K + scol;
    for (int k0 = 0; k0 < K; k0 += 32) {
        *(s16x8*)&As[srow * LDP + scol] = *(const s16x8*)(Au + k0);
        *(s16x8*)&Bs[srow * LDP + scol] = *(const s16x8*)(Bu + k0);
        __syncthreads();
        s16x8 af = *(const s16x8*)&As[(wid * 16 + fr) * LDP + fk];
        #pragma unroll
        for (int j = 0; j < 4; ++j) {
            s16x8 bfv = *(const s16x8*)&Bs[(j * 16 + fr) * LDP + fk];
            acc[j] = __builtin_amdgcn_mfma_f32_16x16x32_bf16(af, bfv, acc[j], 0, 0, 0);
        }
        __syncthreads();
    }
    int drow = bm + wid * 16 + hi2 * 4;
    #pragma unroll
    for (int r = 0; r < 4; ++r) {
        float ps = 0.f;
        #pragma unroll
        for (int j = 0; j < 4; ++j) {
            float v = acc[j][r] + bias[bn + j*16 + fr];
            ps += v * v;
        }
        #pragma unroll
        for (int o = 1; o < 16; o <<= 1) ps += __shfl_xor(ps, o, 64);
        if (fr == 0) parts[(size_t)(drow + r) * 8 + nt] = ps;
    }
    #pragma unroll
    for (int j = 0; j < 4; ++j) {
        int col = bn + j * 16 + fr;
        float bv = bias[col];
        #pragma unroll
        for (int r = 0; r < 4; ++r)
            C[(size_t)(drow + r) * NH + col] = acc[j][r] + bv;
    }
}

// ================= phase kernels =================
// P2: spmm0 (featb -> mat0 hop) | bsq(B1,B1->B2) | btrans(B1)
__global__ __launch_bounds__(256) void k_phase2(const int* __restrict__ rowcnt,
        const int* __restrict__ colidx, const float* __restrict__ vals,
        const __hip_bfloat16* __restrict__ featb, __hip_bfloat16* __restrict__ mat0,
        const float* __restrict__ a_sm,
        const u64* __restrict__ B1, u64* __restrict__ B2, u64* __restrict__ B1T) {
    __shared__ __align__(16) char smem[2560];
    int b = blockIdx.x;
    int t = threadIdx.x;
    int wid = t >> 6, l = t & 63;
    if (b < 2048) {
        role_spmm_bf(b*2 + (t >> 7), t & 127, rowcnt, colidx, vals,
                     (const ushort_t*)featb, NF, (ushort_t*)mat0, K0, a_sm[0]);
    } else if (b < 6144) {
        role_bsq(b - 2048, t, smem, B1, B1, B2);
    } else {
        role_btrans((b - 6144)*4 + wid, wid, l, smem, B1, B1T);
    }
}

// P3: bsq(B1,B2->B3) | btrans(B2) | ymat L0
__global__ __launch_bounds__(256) void k_phase3(const u64* __restrict__ B1,
        const u64* __restrict__ B2, u64* __restrict__ B3, u64* __restrict__ B2T,
        const u64* __restrict__ B1T, const u64* __restrict__ LC,
        const float* __restrict__ a_sm, __hip_bfloat16* __restrict__ mat0) {
    __shared__ __align__(16) char smem[24576];
    int b = blockIdx.x;
    int t = threadIdx.x;
    int wid = t >> 6, l = t & 63;
    if (b < 4096) {
        role_bsq(b, t, smem, B1, B2, B3);
    } else if (b < 5120) {
        role_btrans((b - 4096)*4 + wid, wid, l, smem, B2, B2T);
    } else {
        role_ymat((b - 5120)*8, t, smem, B1, B1T, LC, a_sm, (ushort_t*)mat0, NF, K0);
    }
}

// P4: gemm0 | bsq(B1,B3->B4) | ymat L1
__global__ __launch_bounds__(256) void k_phase4(const __hip_bfloat16* __restrict__ mat0,
        const __hip_bfloat16* __restrict__ Wt0, const float* __restrict__ b0,
        float* __restrict__ tmp0, float* __restrict__ parts0,
        const u64* __restrict__ B1, const u64* __restrict__ B3, u64* __restrict__ B4,
        const u64* __restrict__ B2, const u64* __restrict__ B2T,
        const u64* __restrict__ LC, const float* __restrict__ a_sm,
        __hip_bfloat16* __restrict__ mat1) {
    __shared__ __align__(16) char smem[24576];
    int b = blockIdx.x;
    int t = threadIdx.x;
    if (b < 512) {
        role_gemm(b, t, smem, (const ushort_t*)mat0, (const ushort_t*)Wt0, b0,
                  tmp0, parts0, K0);
    } else if (b < 4608) {
        role_bsq(b - 512, t, smem, B1, B3, B4);
    } else {
        role_ymat((b - 4608)*8, t, smem, B2, B2T, LC, a_sm + 5, (ushort_t*)mat1, NH, K1);
    }
}

// P5: btrans(B4) | spmm_f32s(tmp0 -> u1)
__global__ __launch_bounds__(256) void k_phase5(const u64* __restrict__ B4,
        u64* __restrict__ B4T,
        const int* __restrict__ rowcnt, const int* __restrict__ colidx,
        const float* __restrict__ vals, const float* __restrict__ tmp0,
        const float* __restrict__ parts0, const int* __restrict__ lnflag,
        __hip_bfloat16* __restrict__ u1) {
    __shared__ __align__(16) char smem[2048];
    int b = blockIdx.x;
    int t = threadIdx.x;
    int wid = t >> 6, l = t & 63;
    if (b < 1024) {
        role_btrans(b*4 + wid, wid, l, smem, B4, B4T);
    } else {
        role_spmm_f32s((b - 1024)*4 + wid, l, rowcnt, colidx, vals, tmp0, parts0,
                       *lnflag, (ushort_t*)u1, NH, 1.0f);
    }
}

// P6: spmm_b(u1 -> mat1 hop, alpha5) | ymat L2
__global__ __launch_bounds__(256) void k_phase6(const int* __restrict__ rowcnt,
        const int* __restrict__ colidx, const float* __restrict__ vals,
        const __hip_bfloat16* __restrict__ u1, __hip_bfloat16* __restrict__ mat1,
        const float* __restrict__ a_sm,
        const u64* __restrict__ B4, const u64* __restrict__ B4T,
        const u64* __restrict__ LC, __hip_bfloat16* __restrict__ mat2) {
    __shared__ __align__(16) char smem[24576];
    int b = blockIdx.x;
    int t = threadIdx.x;
    if (b < 1024) {
        role_spmm_bf(b*4 + (t >> 6), t & 63, rowcnt, colidx, vals,
                     (const ushort_t*)u1, NH, (ushort_t*)mat1, K1, a_sm[5]);
    } else {
        role_ymat((b - 1024)*8, t, smem, B4, B4T, LC, a_sm + 10, (ushort_t*)mat2, NH, K1);
    }
}

__global__ __launch_bounds__(256) void k_gemm(const __hip_bfloat16* __restrict__ mat,
        const __hip_bfloat16* __restrict__ Wt, const float* __restrict__ bias,
        float* __restrict__ C, float* __restrict__ parts, int K) {
    __shared__ __align__(16) char smem[2 * 64 * LDP * 2];
    role_gemm(blockIdx.x, threadIdx.x, smem, (const ushort_t*)mat, (const ushort_t*)Wt,
              bias, C, parts, K);
}

__global__ __launch_bounds__(256) void k_spmm_f(const int* __restrict__ rc,
        const int* __restrict__ ci, const float* __restrict__ vl,
        const float* __restrict__ src, const float* __restrict__ parts,
        const int* __restrict__ lnflag, __hip_bfloat16* __restrict__ Y,
        int ystride) {
    role_spmm_f32s(blockIdx.x*4 + (threadIdx.x >> 6), threadIdx.x & 63, rc, ci, vl,
                   src, parts, *lnflag, (ushort_t*)Y, ystride, 1.0f);
}

__global__ __launch_bounds__(256) void k_spmm_b(const int* __restrict__ rc,
        const int* __restrict__ ci, const float* __restrict__ vl,
        const __hip_bfloat16* __restrict__ X, __hip_bfloat16* __restrict__ Y,
        int ystride, const float* __restrict__ a_sm, int ai) {
    float alpha = (ai >= 0) ? a_sm[ai] : 1.0f;
    role_spmm_bf(blockIdx.x*4 + (threadIdx.x >> 6), threadIdx.x & 63, rc, ci, vl,
                 (const ushort_t*)X, NH, (ushort_t*)Y, ystride, alpha);
}

// ================= final: all-layer l2norm + max + relu + W2 + log_softmax =================
__global__ __launch_bounds__(256) void k_l2final(const float* __restrict__ tmp0,
        const float* __restrict__ parts0, const float* __restrict__ tmp1,
        const float* __restrict__ parts1, const float* __restrict__ tmp2,
        const float* __restrict__ parts2, const float* __restrict__ feat0,
        const float* __restrict__ W2, const float* __restrict__ b2,
        const int* __restrict__ lnflag, float* __restrict__ out) {
    int rb = blockIdx.x * 8;
    int t = threadIdx.x;
    __shared__ float rows[8][NF + NH];
    __shared__ float part[8][8][32];
    for (int r = 0; r < 8; ++r) {
        const float* f0 = feat0 + (size_t)(rb + r) * NF;
        for (int c = t; c < NF; c += 256) rows[r][c] = fmaxf(f0[c], 0.f);
    }
    int wid = t >> 6, lane = t & 63;
    int ln = *lnflag;
    #pragma unroll
    for (int rr = 0; rr < 2; ++rr) {
        int r = wid * 2 + rr;
        int row = rb + r;
        float s0, s1, s2;
        {
            float4 a0 = *(const float4*)&parts0[row*8], b0v = *(const float4*)&parts0[row*8+4];
            float4 a1 = *(const float4*)&parts1[row*8], b1v = *(const float4*)&parts1[row*8+4];
            float4 a2 = *(const float4*)&parts2[row*8], b2v = *(const float4*)&parts2[row*8+4];
            float q0 = a0.x+a0.y+a0.z+a0.w + b0v.x+b0v.y+b0v.z+b0v.w;
            float q1 = a1.x+a1.y+a1.z+a1.w + b1v.x+b1v.y+b1v.z+b1v.w;
            float q2 = a2.x+a2.y+a2.z+a2.w + b2v.x+b2v.y+b2v.z+b2v.w;
            s0 = ln ? 1.0f / fmaxf(sqrtf(q0), 1e-12f) : 1.0f;
            s1 = ln ? 1.0f / fmaxf(sqrtf(q1), 1e-12f) : 1.0f;
            s2 = ln ? 1.0f / fmaxf(sqrtf(q2), 1e-12f) : 1.0f;
        }
        const float4* t0 = (const float4*)(tmp0 + (size_t)row * NH + lane * 8);
        const float4* t1 = (const float4*)(tmp1 + (size_t)row * NH + lane * 8);
        const float4* t2 = (const float4*)(tmp2 + (size_t)row * NH + lane * 8);
        float* dst = &rows[r][NF + lane * 8];
        #pragma unroll
        for (int h = 0; h < 2; ++h) {
            float4 v0 = t0[h], v1 = t1[h], v2 = t2[h];
            dst[h*4+0] = fmaxf(fmaxf(fmaxf(v0.x*s0, v1.x*s1), v2.x*s2), 0.f);
            dst[h*4+1] = fmaxf(fmaxf(fmaxf(v0.y*s0, v1.y*s1), v2.y*s2), 0.f);
            dst[h*4+2] = fmaxf(fmaxf(fmaxf(v0.z*s0, v1.z*s1), v2.z*s2), 0.f);
            dst[h*4+3] = fmaxf(fmaxf(fmaxf(v0.w*s0, v1.w*s1), v2.w*s2), 0.f);
        }
    }
    __syncthreads();
    int c = t & 31, g = t >> 5;
    float acc[8] = {0,0,0,0,0,0,0,0};
    for (int k = g * 192; k < (g + 1) * 192; ++k) {
        float w = W2[(size_t)k * NC + c];
        #pragma unroll
        for (int r = 0; r < 8; ++r) acc[r] += rows[r][k] * w;
    }
    #pragma unroll
    for (int r = 0; r < 8; ++r) part[g][r][c] = acc[r];
    __syncthreads();
    int r = g;
    float lg = b2[c];
    #pragma unroll
    for (int gg = 0; gg < 8; ++gg) lg += part[gg][r][c];
    float m = lg;
    #pragma unroll
    for (int o = 16; o > 0; o >>= 1) m = fmaxf(m, __shfl_xor(m, o, 32));
    float e = expf(lg - m), s = e;
    #pragma unroll
    for (int o = 16; o > 0; o >>= 1) s += __shfl_xor(s, o, 32);
    out[(size_t)(rb + r) * NC + c] = lg - m - logf(s);
}

extern "C" void kernel_launch(void* const* d_in, const int* in_sizes, int n_in,
                              void* d_out, int out_size, void* d_ws, size_t ws_size,
                              hipStream_t stream) {
    const float* adj      = (const float*)d_in[0];
    const float* features = (const float*)d_in[1];
    const float* y        = (const float*)d_in[2];
    const float* W0       = (const float*)d_in[3];
    const float* b0       = (const float*)d_in[4];
    const float* W1_0     = (const float*)d_in[5];
    const float* b1_0     = (const float*)d_in[6];
    const float* W1_1     = (const float*)d_in[7];
    const float* b1_1     = (const float*)d_in[8];
    const float* W2       = (const float*)d_in[9];
    const float* b2       = (const float*)d_in[10];
    const float* alphas   = (const float*)d_in[11];
    const int*   lnflag   = (const int*)d_in[12];
    float* out = (float*)d_out;

    char* ws = (char*)d_ws;
    size_t off = 0;
    auto alloc = [&](size_t bytes) -> char* {
        char* p = ws + off;
        off = (off + bytes + 255) & ~(size_t)255;
        return p;
    };
    float* a_sm   = (float*)alloc(16 * 4);
    int*   rowcnt = (int*)alloc((size_t)NN * 4);
    int*   colidx = (int*)alloc((size_t)NN * 64 * 4);
    float* vals   = (float*)alloc((size_t)NN * 64 * 4);
    u64* B1  = (u64*)alloc((size_t)NN * 64 * 8);
    u64* B2  = (u64*)alloc((size_t)NN * 64 * 8);
    u64* B3  = (u64*)alloc((size_t)NN * 64 * 8);
    u64* B4  = (u64*)alloc((size_t)NN * 64 * 8);
    u64* B1T = (u64*)alloc((size_t)NN * 64 * 8);
    u64* B2T = (u64*)alloc((size_t)NN * 64 * 8);
    u64* B4T = (u64*)alloc((size_t)NN * 64 * 8);
    u64* LC  = (u64*)alloc((size_t)NC * 64 * 8);
    __hip_bfloat16* featb = (__hip_bfloat16*)alloc((size_t)NN * NF * 2);
    __hip_bfloat16* t1b   = (__hip_bfloat16*)alloc((size_t)NN * NH * 2);
    __hip_bfloat16* t2b   = (__hip_bfloat16*)alloc((size_t)NN * NH * 2);
    __hip_bfloat16* mat0  = (__hip_bfloat16*)alloc((size_t)NN * K0 * 2);
    __hip_bfloat16* mat1  = (__hip_bfloat16*)alloc((size_t)NN * K1 * 2);
    __hip_bfloat16* mat2  = (__hip_bfloat16*)alloc((size_t)NN * K1 * 2);
    __hip_bfloat16* Wt0   = (__hip_bfloat16*)alloc((size_t)NH * K0 * 2);
    __hip_bfloat16* Wt1   = (__hip_bfloat16*)alloc((size_t)NH * K1 * 2);
    __hip_bfloat16* Wt2   = (__hip_bfloat16*)alloc((size_t)NH * K1 * 2);
    float* tmp0   = (float*)alloc((size_t)NN * NH * 4);
    float* tmp1   = (float*)alloc((size_t)NN * NH * 4);
    float* tmp2   = (float*)alloc((size_t)NN * NH * 4);
    float* parts0 = (float*)alloc((size_t)NN * 8 * 4);
    float* parts1 = (float*)alloc((size_t)NN * 8 * 4);
    float* parts2 = (float*)alloc((size_t)NN * 8 * 4);

    // L1: build | featbf | labelbits | Wt | alphas
    k_setup<<<6305, 256, 0, stream>>>(adj, features, featb, y, LC, W0, W1_0, W1_1,
                                      Wt0, Wt1, Wt2, alphas, a_sm,
                                      B1, rowcnt, colidx, vals);
    // L2: spmm0 | bsq(B1,B1->B2) | btrans(B1)
    k_phase2<<<7168, 256, 0, stream>>>(rowcnt, colidx, vals, featb, mat0, a_sm,
                                       B1, B2, B1T);
    // L3: bsq(B1,B2->B3) | btrans(B2) | ymat L0
    k_phase3<<<5632, 256, 0, stream>>>(B1, B2, B3, B2T, B1T, LC, a_sm, mat0);
    // L4: gemm0 | bsq(B1,B3->B4) | ymat L1
    k_phase4<<<5120, 256, 0, stream>>>(mat0, Wt0, b0, tmp0, parts0,
                                       B1, B3, B4, B2, B2T, LC, a_sm, mat1);
    // L5: btrans(B4) | spmm_f32s(tmp0 -> u1=t1b)
    k_phase5<<<2048, 256, 0, stream>>>(B4, B4T, rowcnt, colidx, vals,
                                       tmp0, parts0, lnflag, t1b);
    // L6: spmm_b(t1b -> mat1 hop, a5) | ymat L2
    k_phase6<<<1536, 256, 0, stream>>>(rowcnt, colidx, vals, t1b, mat1, a_sm,
                                       B4, B4T, LC, mat2);
    // L7: gemm1
    k_gemm<<<512, 256, 0, stream>>>(mat1, Wt1, b1_0, tmp1, parts1, K1);
    // L8-L11: layer-2 hop chain (adj^4 @ norm(tmp1))
    k_spmm_f<<<NN/4, 256, 0, stream>>>(rowcnt, colidx, vals, tmp1, parts1, lnflag, t1b, NH);
    k_spmm_b<<<NN/4, 256, 0, stream>>>(rowcnt, colidx, vals, t1b, t2b, NH, a_sm, -1);
    k_spmm_b<<<NN/4, 256, 0, stream>>>(rowcnt, colidx, vals, t2b, t1b, NH, a_sm, -1);
    k_spmm_b<<<NN/4, 256, 0, stream>>>(rowcnt, colidx, vals, t1b, mat2, K1, a_sm, 10);
    // L12: gemm2
    k_gemm<<<512, 256, 0, stream>>>(mat2, Wt2, b1_1, tmp2, parts2, K1);
    // L13: fused final
    k_l2final<<<NN/8, 256, 0, stream>>>(tmp0, parts0, tmp1, parts1, tmp2, parts2,
                                        features, W2, b2, lnflag, out);
}